// Round 12
// baseline (201.789 us; speedup 1.0000x reference)
//
#include <hip/hip_runtime.h>
#include <hip/hip_bf16.h>
#include <stdint.h>

// ---------------------------------------------------------------------------
// TrafficGNN: 2-layer GCN + skip, N=50000, E=1.6M, dims 256->128->128.
// R12 changes vs R11 (171.5us):
//  - aggregate: two SEQUENTIAL 64B half-row passes (fp8 half-row = 1 line),
//    4 nodes/wave x 16 lanes x 4B. Footprint/pass = 3.2MB < 4MB L2 ->
//    capacity misses ~0; requests/edge UNCHANGED vs R11 (R6's failure mode
//    -- request doubling -- does not apply). Compulsory fetch ~51MB/layer.
//  - k_wtall fused into k_count (k_wtcount, block-range split): -1 launch.
// ---------------------------------------------------------------------------

typedef __attribute__((ext_vector_type(8))) short bf16x8;
typedef __attribute__((ext_vector_type(4))) float f32x4;
typedef __attribute__((ext_vector_type(2))) float f32x2;

#define NB 392        // dst buckets (392*128 = 50176 >= 50000)
#define NPB 128       // nodes per bucket (pow2: bucket = dst>>7)
#define CHUNK 2048    // edges per k_count/k_scatter block

__device__ __forceinline__ short f2bf(float f) {
  uint32_t u = __float_as_uint(f);
  u += 0x7fffu + ((u >> 16) & 1u);   // round-to-nearest-even
  return (short)(u >> 16);
}

// --- fp8 e4m3fn encode/decode (HW cvt preferred, software fallback) ---------
#if __has_builtin(__builtin_amdgcn_cvt_pk_fp8_f32)
__device__ __forceinline__ uint32_t f32_to_fp8(float x) {
  return (uint32_t)__builtin_amdgcn_cvt_pk_fp8_f32(x, x, 0, false) & 0xffu;
}
#else
__device__ __forceinline__ uint32_t f32_to_fp8(float x) {
  uint32_t u = __float_as_uint(x);
  uint32_t s = (u >> 24) & 0x80u;
  float ax = fabsf(x);
  if (ax > 448.f) ax = 448.f;
  uint32_t b;
  if (ax < 0.015625f) {
    b = (uint32_t)(ax * 512.f + 0.5f);
    if (b > 8) b = 8;
  } else {
    uint32_t au = __float_as_uint(ax);
    uint32_t exp = au >> 23;
    uint32_t man = au & 0x7fffffu;
    uint32_t keep = man >> 20;
    uint32_t rem = man & 0xFFFFFu;
    uint32_t rnd = (rem > 0x80000u) || (rem == 0x80000u && (keep & 1u));
    uint32_t code = ((exp - 120u) << 3) | keep;
    code += rnd;
    if (code > 0x7Eu) code = 0x7Eu;
    b = code;
  }
  return b | s;
}
#endif

#if __has_builtin(__builtin_amdgcn_cvt_pk_f32_fp8)
template <bool HI>
__device__ __forceinline__ f32x2 fp8x2_to_f32(uint32_t u) {
  return __builtin_amdgcn_cvt_pk_f32_fp8((int)u, HI);   // HI is a literal
}
#else
__device__ __forceinline__ float fp8_to_f32_1(uint32_t b) {
  uint32_t s = (b & 0x80u) << 24;
  uint32_t e = (b >> 3) & 0xFu;
  uint32_t m = b & 7u;
  float v = e ? __uint_as_float(((e + 120u) << 23) | (m << 20))
              : (float)m * 0.001953125f;
  return __uint_as_float(__float_as_uint(v) | s);
}
template <bool HI>
__device__ __forceinline__ f32x2 fp8x2_to_f32(uint32_t u) {
  uint32_t h = HI ? (u >> 16) : u;
  f32x2 r;
  r[0] = fp8_to_f32_1(h & 0xffu);
  r[1] = fp8_to_f32_1((h >> 8) & 0xffu);
  return r;
}
#endif

// --- fused: per-chunk bucket histogram (blocks [0,nblk)) + weight transpose
//     (blocks [nblk, nblk+384)) ------------------------------------------
__global__ __launch_bounds__(256) void k_wtcount(const int* __restrict__ dst,
                                                 int* __restrict__ count, int E, int nblk,
                                                 const float* __restrict__ W1,
                                                 const float* __restrict__ W2,
                                                 const float* __restrict__ Ws,
                                                 const float* __restrict__ Wf,
                                                 short* __restrict__ W1T,
                                                 short* __restrict__ W2T,
                                                 short* __restrict__ WsT,
                                                 short* __restrict__ WfT) {
  int t = threadIdx.x;
  if ((int)blockIdx.x >= nblk) {
    int i = ((int)blockIdx.x - nblk) * 256 + t;
    const float* W; short* WT; int K, off;
    if (i < 32768)      { W = W1; WT = W1T; K = 256; off = 0; }
    else if (i < 49152) { W = W2; WT = W2T; K = 128; off = 32768; }
    else if (i < 81920) { W = Ws; WT = WsT; K = 256; off = 49152; }
    else if (i < 98304) { W = Wf; WT = WfT; K = 128; off = 81920; }
    else return;
    int j = i - off;
    int k = j >> 7, nn = j & 127;           // N = 128 always
    WT[nn * K + k] = f2bf(W[j]);
    return;
  }
  __shared__ int h[512];
  h[t] = 0; h[t + 256] = 0;
  __syncthreads();
  int base = blockIdx.x * CHUNK;
#pragma unroll
  for (int i = 0; i < CHUNK / 256; ++i) {
    int idx = base + i * 256 + t;
    if (idx < E) atomicAdd(&h[dst[idx] >> 7], 1);
  }
  __syncthreads();
  if (t < NB) count[blockIdx.x * NB + t] = h[t];
  if (t + 256 < NB) count[blockIdx.x * NB + t + 256] = h[t + 256];
}

// --- stage 2: per-bucket exclusive scan over chunks (nblk <= 1024) ----------
__global__ __launch_bounds__(1024) void k_colscan(int* __restrict__ count,
                                                  int* __restrict__ btot, int nblk) {
  __shared__ int s[1024];
  int t = threadIdx.x, b = blockIdx.x;
  int v = (t < nblk) ? count[t * NB + b] : 0;
  s[t] = v;
  __syncthreads();
  for (int off = 1; off < 1024; off <<= 1) {
    int u = (t >= off) ? s[t - off] : 0;
    __syncthreads();
    s[t] += u;
    __syncthreads();
  }
  if (t < nblk) count[t * NB + b] = s[t] - v;   // exclusive within column
  if (t == 1023) btot[b] = s[1023];
}

// --- stage 3: exclusive scan of NB bucket totals ----------------------------
__global__ __launch_bounds__(256) void k_btot_scan(const int* __restrict__ btot,
                                                   int* __restrict__ bucket_start,
                                                   int* __restrict__ row_start, int n) {
  __shared__ int a[512];
  __shared__ int p[256];
  int t = threadIdx.x;
  a[t] = (t < NB) ? btot[t] : 0;
  a[t + 256] = (t + 256 < NB) ? btot[t + 256] : 0;
  __syncthreads();
  int pv = a[2 * t] + a[2 * t + 1];
  p[t] = pv;
  __syncthreads();
  for (int off = 1; off < 256; off <<= 1) {
    int u = (t >= off) ? p[t - off] : 0;
    __syncthreads();
    p[t] += u;
    __syncthreads();
  }
  int pex = p[t] - pv;
  if (2 * t < NB + 1) bucket_start[2 * t] = pex;
  if (2 * t + 1 < NB + 1) bucket_start[2 * t + 1] = pex + a[2 * t];
  if (t == 255) row_start[n] = p[255];   // = E
}

// --- stage 4: LDS multisplit + coalesced copy-out (packed int) --------------
__global__ __launch_bounds__(256) void k_scatter(const int* __restrict__ src,
                                                 const int* __restrict__ dst,
                                                 const int* __restrict__ colscan,
                                                 const int* __restrict__ bucket_start,
                                                 int* __restrict__ pairs, int E) {
  __shared__ int gcur[NB];
  __shared__ int hist[512];
  __shared__ int sstart[512];
  __shared__ int cur[512];
  __shared__ int p[256];
  __shared__ int2 stage[CHUNK];
  __shared__ int tot;
  int t = threadIdx.x;
  if (t < NB) gcur[t] = bucket_start[t] + colscan[blockIdx.x * NB + t];
  if (t + 256 < NB) gcur[t + 256] = bucket_start[t + 256] + colscan[blockIdx.x * NB + t + 256];
  hist[t] = 0; hist[t + 256] = 0;
  __syncthreads();
  int base = blockIdx.x * CHUNK;
  int mys[CHUNK / 256], myd[CHUNK / 256];
#pragma unroll
  for (int i = 0; i < CHUNK / 256; ++i) {
    int idx = base + i * 256 + t;
    if (idx < E) {
      mys[i] = src[idx]; myd[i] = dst[idx];
      atomicAdd(&hist[myd[i] >> 7], 1);
    } else myd[i] = -1;
  }
  __syncthreads();
  // exclusive scan of hist[512] with 256 threads (pair trick)
  int pv = hist[2 * t] + hist[2 * t + 1];
  p[t] = pv;
  __syncthreads();
  for (int off = 1; off < 256; off <<= 1) {
    int u = (t >= off) ? p[t - off] : 0;
    __syncthreads();
    p[t] += u;
    __syncthreads();
  }
  int pex = p[t] - pv;
  sstart[2 * t] = pex;                   cur[2 * t] = pex;
  sstart[2 * t + 1] = pex + hist[2 * t]; cur[2 * t + 1] = pex + hist[2 * t];
  if (t == 255) tot = p[255];
  __syncthreads();
#pragma unroll
  for (int i = 0; i < CHUNK / 256; ++i) {
    if (myd[i] >= 0) {
      int slot = atomicAdd(&cur[myd[i] >> 7], 1);
      stage[slot] = int2{mys[i], myd[i]};
    }
  }
  __syncthreads();
  // coalesced copy-out: consecutive slots of a segment -> consecutive global
  int total = tot;
  for (int i = t; i < total; i += 256) {
    int2 pr = stage[i];
    int b = pr.y >> 7;
    pairs[gcur[b] + (i - sstart[b])] = (pr.x << 7) | (pr.y & 127);
  }
}

// --- stage 5: bucket -> CSR (+ row_start, dinv); 16KB single-owner window ---
__global__ __launch_bounds__(256) void k_bucket2csr(const int* __restrict__ pairs,
                                                    const int* __restrict__ bucket_start,
                                                    int* __restrict__ row_start,
                                                    float* __restrict__ dinv,
                                                    int* __restrict__ csr_src, int n) {
  __shared__ int cnt[NPB];
  __shared__ int scn[NPB];
  __shared__ int cur[NPB];
  int b = blockIdx.x, t = threadIdx.x;
  int bs = bucket_start[b], be = bucket_start[b + 1];
  int nodeBase = b << 7;
  if (t < NPB) cnt[t] = 0;
  __syncthreads();
  for (int i = bs + t; i < be; i += 256)
    atomicAdd(&cnt[pairs[i] & 127], 1);
  __syncthreads();
  int v = (t < NPB) ? cnt[t] : 0;
  if (t < NPB) scn[t] = v;
  __syncthreads();
  for (int off = 1; off < NPB; off <<= 1) {
    int u = (t >= off && t < NPB) ? scn[t - off] : 0;
    __syncthreads();
    if (t < NPB) scn[t] += u;
    __syncthreads();
  }
  if (t < NPB) {
    int ex = scn[t] - v;
    cur[t] = ex;
    int node = nodeBase + t;
    if (node < n) {
      row_start[node] = bs + ex;
      dinv[node] = rsqrtf((float)(v + 1));   // +1 self-loop
    }
  }
  __syncthreads();
  for (int i = bs + t; i < be; i += 256) {
    int packed = pairs[i];
    int pos = bs + atomicAdd(&cur[packed & 127], 1);
    csr_src[pos] = packed >> 7;
  }
}

// === LDS-staged panel GEMM ==================================================
__device__ __forceinline__ void stage_panel(short* lB, const short* __restrict__ BT,
                                            int K, int p, int t) {
#pragma unroll
  for (int i = 0; i < 8; ++i) {
    int ch = t + i * 256;            // 2048 chunks of 8 shorts
    int nrow = ch >> 4;
    int kl = (ch & 15) << 3;         // local k (shorts)
    bf16x8 v = *(const bf16x8*)(BT + (size_t)nrow * K + p * 128 + kl);
    int byte = nrow * 256 + ((kl << 1) ^ ((nrow & 7) << 4));
    *(bf16x8*)((char*)lB + byte) = v;
  }
}

__device__ __forceinline__ bf16x8 lds_bfrag(const short* lB, int c, int r, int g, int k0) {
  int nrow = c * 16 + r;
  int byte = nrow * 256 + (((k0 + g * 8) << 1) ^ ((nrow & 7) << 4));
  return *(const bf16x8*)((const char*)lB + byte);
}

__device__ __forceinline__ bf16x8 load_a_f32(const float* A, int row, int K, int kidx) {
  const f32x4* p = (const f32x4*)(A + (size_t)row * K + kidx);
  f32x4 v0 = p[0], v1 = p[1];
  bf16x8 a;
  a[0] = f2bf(v0[0]); a[1] = f2bf(v0[1]); a[2] = f2bf(v0[2]); a[3] = f2bf(v0[3]);
  a[4] = f2bf(v1[0]); a[5] = f2bf(v1[1]); a[6] = f2bf(v1[2]); a[7] = f2bf(v1[3]);
  return a;
}

// k_gemm: [M,K] @ WT[128,K] -> scaled (fp8 bytes), epilogue *dinv[row]
template <bool A_F32, int K>
__global__ __launch_bounds__(256, 4) void k_gemm(const void* __restrict__ Av,
                                                 const short* __restrict__ BT,
                                                 const float* __restrict__ dinv,
                                                 uint8_t* __restrict__ outv, int M) {
  __shared__ short lB[128 * 128];   // 32KB
  int t = threadIdx.x;
  int wave = t >> 6, lane = t & 63;
  int r = lane & 15, g = lane >> 4;
  int rowBase = blockIdx.x * 128 + wave * 32;

  f32x4 acc[2][8];
#pragma unroll
  for (int m = 0; m < 2; ++m)
#pragma unroll
    for (int c = 0; c < 8; ++c) acc[m][c] = f32x4{0.f, 0.f, 0.f, 0.f};

  int arow[2];
#pragma unroll
  for (int m = 0; m < 2; ++m) {
    int row = rowBase + m * 16 + r;
    arow[m] = (row < M) ? row : (M - 1);   // clamp: no early return (barriers)
  }

  for (int p = 0; p < K / 128; ++p) {
    stage_panel(lB, BT, K, p, t);
    __syncthreads();
#pragma unroll
    for (int k0 = 0; k0 < 128; k0 += 32) {
      int kidx = p * 128 + k0 + g * 8;
      bf16x8 af[2];
#pragma unroll
      for (int m = 0; m < 2; ++m) {
        if constexpr (A_F32) af[m] = load_a_f32((const float*)Av, arow[m], K, kidx);
        else af[m] = *(const bf16x8*)((const short*)Av + (size_t)arow[m] * K + kidx);
      }
#pragma unroll
      for (int c = 0; c < 8; ++c) {
        bf16x8 bfrag = lds_bfrag(lB, c, r, g, k0);
#pragma unroll
        for (int m = 0; m < 2; ++m)
          acc[m][c] = __builtin_amdgcn_mfma_f32_16x16x32_bf16(af[m], bfrag, acc[m][c], 0, 0, 0);
      }
    }
    __syncthreads();
  }

#pragma unroll
  for (int m = 0; m < 2; ++m)
#pragma unroll
    for (int j = 0; j < 4; ++j) {
      int rr = rowBase + m * 16 + g * 4 + j;
      if (rr < M) {
        float dv = dinv[rr];
#pragma unroll
        for (int c = 0; c < 8; ++c)
          outv[(size_t)rr * 128 + c * 16 + r] = (uint8_t)f32_to_fp8(acc[m][c][j] * dv);
      }
    }
}

// --- fused final: out = x@WsT + h2@WfT + (bs+bf), 3 panels through 32KB -----
template <int K1, int K2>
__global__ __launch_bounds__(256, 4) void k_gemm_dual(const float* __restrict__ A1,
                                                      const short* __restrict__ B1T,
                                                      const short* __restrict__ A2,
                                                      const short* __restrict__ B2T,
                                                      const float* __restrict__ bias1,
                                                      const float* __restrict__ bias2,
                                                      float* __restrict__ out, int M) {
  __shared__ short lB[128 * 128];   // 32KB
  int t = threadIdx.x;
  int wave = t >> 6, lane = t & 63;
  int r = lane & 15, g = lane >> 4;
  int rowBase = blockIdx.x * 128 + wave * 32;

  f32x4 acc[2][8];
#pragma unroll
  for (int m = 0; m < 2; ++m)
#pragma unroll
    for (int c = 0; c < 8; ++c) acc[m][c] = f32x4{0.f, 0.f, 0.f, 0.f};

  int arow[2];
#pragma unroll
  for (int m = 0; m < 2; ++m) {
    int row = rowBase + m * 16 + r;
    arow[m] = (row < M) ? row : (M - 1);
  }

  for (int p = 0; p < K1 / 128; ++p) {
    stage_panel(lB, B1T, K1, p, t);
    __syncthreads();
#pragma unroll
    for (int k0 = 0; k0 < 128; k0 += 32) {
      int kidx = p * 128 + k0 + g * 8;
      bf16x8 af[2];
#pragma unroll
      for (int m = 0; m < 2; ++m) af[m] = load_a_f32(A1, arow[m], K1, kidx);
#pragma unroll
      for (int c = 0; c < 8; ++c) {
        bf16x8 bfrag = lds_bfrag(lB, c, r, g, k0);
#pragma unroll
        for (int m = 0; m < 2; ++m)
          acc[m][c] = __builtin_amdgcn_mfma_f32_16x16x32_bf16(af[m], bfrag, acc[m][c], 0, 0, 0);
      }
    }
    __syncthreads();
  }
  for (int p = 0; p < K2 / 128; ++p) {
    stage_panel(lB, B2T, K2, p, t);
    __syncthreads();
#pragma unroll
    for (int k0 = 0; k0 < 128; k0 += 32) {
      int kidx = p * 128 + k0 + g * 8;
      bf16x8 af[2];
#pragma unroll
      for (int m = 0; m < 2; ++m)
        af[m] = *(const bf16x8*)(A2 + (size_t)arow[m] * K2 + kidx);
#pragma unroll
      for (int c = 0; c < 8; ++c) {
        bf16x8 bfrag = lds_bfrag(lB, c, r, g, k0);
#pragma unroll
        for (int m = 0; m < 2; ++m)
          acc[m][c] = __builtin_amdgcn_mfma_f32_16x16x32_bf16(af[m], bfrag, acc[m][c], 0, 0, 0);
      }
    }
    __syncthreads();
  }

#pragma unroll
  for (int m = 0; m < 2; ++m)
#pragma unroll
    for (int j = 0; j < 4; ++j) {
      int rr = rowBase + m * 16 + g * 4 + j;
      if (rr < M) {
#pragma unroll
        for (int c = 0; c < 8; ++c) {
          int cc = c * 16 + r;
          out[(size_t)rr * 128 + cc] = acc[m][c][j] + bias1[cc] + bias2[cc];
        }
      }
    }
}

// --- CSR gather, fp8 HALF-row pass: 4 nodes/wave, 16 lanes x 4B = 64B/row ---
// pass p gathers bytes [64p, 64p+64) (one cacheline) of each src row.
// Footprint/pass = 3.2MB < 4MB L2. Lane l covers feats [p*64+4l, +4).
__global__ __launch_bounds__(256, 8) void k_aggregate(const uint8_t* __restrict__ scaled,
                                                      const float* __restrict__ dinv,
                                                      const float* __restrict__ bias,
                                                      const int* __restrict__ row_start,
                                                      const int* __restrict__ csr_src,
                                                      short* __restrict__ hout,
                                                      int n, int pass) {
  int lane = threadIdx.x & 63;
  int l = lane & 15;                       // lane within quarter-wave
  int node = (blockIdx.x * 4 + (threadIdx.x >> 6)) * 4 + (lane >> 4);
  if (node >= n) return;
  const uint32_t* __restrict__ su = (const uint32_t*)scaled;  // row = 32 uints
  uint32_t rb = (uint32_t)pass * 16u + l;  // uint offset within row

  uint32_t u = su[(uint32_t)node * 32u + rb];   // self loop
  f32x2 a0 = fp8x2_to_f32<false>(u), a1 = fp8x2_to_f32<true>(u);
  float s0 = a0[0], s1 = a0[1], s2 = a1[0], s3 = a1[1];

  int beg = row_start[node], end = row_start[node + 1];
  int deg = end - beg;
  int nfull = deg & ~7;
  int j = beg;
  if (nfull) {
    uint32_t offv[8];
#pragma unroll
    for (int q = 0; q < 8; ++q) offv[q] = (uint32_t)csr_src[beg + q] * 32u + rb;
    for (int base = 8;; base += 8) {
      uint32_t v[8];
#pragma unroll
      for (int q = 0; q < 8; ++q) v[q] = su[offv[q]];
      bool more = (base < nfull);
      if (more) {
#pragma unroll
        for (int q = 0; q < 8; ++q) offv[q] = (uint32_t)csr_src[beg + base + q] * 32u + rb;
      }
#pragma unroll
      for (int q = 0; q < 8; ++q) {
        f32x2 lo = fp8x2_to_f32<false>(v[q]), hi = fp8x2_to_f32<true>(v[q]);
        s0 += lo[0]; s1 += lo[1]; s2 += hi[0]; s3 += hi[1];
      }
      if (!more) break;
    }
    j = beg + nfull;
  }
  for (; j < end; ++j) {
    uint32_t v = su[(uint32_t)csr_src[j] * 32u + rb];
    f32x2 lo = fp8x2_to_f32<false>(v), hi = fp8x2_to_f32<true>(v);
    s0 += lo[0]; s1 += lo[1]; s2 += hi[0]; s3 += hi[1];
  }

  float di = dinv[node];
  int col = pass * 64 + l * 4;
  float h0 = fmaxf(fmaf(s0, di, bias[col]), 0.f);
  float h1 = fmaxf(fmaf(s1, di, bias[col + 1]), 0.f);
  float h2 = fmaxf(fmaf(s2, di, bias[col + 2]), 0.f);
  float h3 = fmaxf(fmaf(s3, di, bias[col + 3]), 0.f);
  uint2 o;
  o.x = (uint32_t)(uint16_t)f2bf(h0) | ((uint32_t)(uint16_t)f2bf(h1) << 16);
  o.y = (uint32_t)(uint16_t)f2bf(h2) | ((uint32_t)(uint16_t)f2bf(h3) << 16);
  ((uint2*)hout)[(uint32_t)node * 32u + rb] = o;   // hout row = 32 uint2
}

extern "C" void kernel_launch(void* const* d_in, const int* in_sizes, int n_in,
                              void* d_out, int out_size, void* d_ws, size_t ws_size,
                              hipStream_t stream) {
  const float* x  = (const float*)d_in[0];
  const int* ei   = (const int*)d_in[1];
  const float* W1 = (const float*)d_in[2];
  const float* b1 = (const float*)d_in[3];
  const float* W2 = (const float*)d_in[4];
  const float* b2 = (const float*)d_in[5];
  const float* Wsk = (const float*)d_in[6];
  const float* bsk = (const float*)d_in[7];
  const float* Wf = (const float*)d_in[8];
  const float* bf_ = (const float*)d_in[9];

  const int n = in_sizes[0] / 256;
  const int E = in_sizes[1] / 2;
  const int* src = ei;
  const int* dst = ei + E;

  char* p = (char*)d_ws;
  auto alloc = [&](size_t bytes) -> char* {
    char* r = p;
    p += (bytes + 255) & ~(size_t)255;
    return r;
  };
  // pairs (6.4MB packed, dead after k_bucket2csr) aliases scaled (6.4MB fp8)
  char* buf0       = alloc((size_t)E * 4);                // 6.4 MB
  int* pairs       = (int*)buf0;
  uint8_t* scaled  = (uint8_t*)buf0;
  short* hbuf      = (short*)alloc((size_t)n * 128 * 2);  // 12.8 MB
  int* csr_src     = (int*)alloc((size_t)E * 4);          // 6.4 MB
  int* count       = (int*)alloc((size_t)1024 * NB * 4);  // 1.6 MB max
  int* btot        = (int*)alloc(NB * 4);
  int* bucket_start= (int*)alloc((NB + 1) * 4);
  int* row_start   = (int*)alloc((size_t)(n + 1) * 4);
  float* dinv      = (float*)alloc((size_t)n * 4);
  short* W1T       = (short*)alloc(256 * 128 * 2);
  short* W2T       = (short*)alloc(128 * 128 * 2);
  short* WsT       = (short*)alloc(256 * 128 * 2);
  short* WfT       = (short*)alloc(128 * 128 * 2);

  const int nblk = (E + CHUNK - 1) / CHUNK;   // 782 for E=1.6M (<= 1024)
  const int wtblk = (98304 + 255) / 256;      // 384
  k_wtcount<<<nblk + wtblk, 256, 0, stream>>>(dst, count, E, nblk,
                                              W1, W2, Wsk, Wf, W1T, W2T, WsT, WfT);
  k_colscan<<<NB, 1024, 0, stream>>>(count, btot, nblk);
  k_btot_scan<<<1, 256, 0, stream>>>(btot, bucket_start, row_start, n);
  k_scatter<<<nblk, 256, 0, stream>>>(src, dst, count, bucket_start, pairs, E);
  k_bucket2csr<<<NB, 256, 0, stream>>>(pairs, bucket_start, row_start, dinv, csr_src, n);

  const int gblocks = (n + 127) / 128;   // 391
  const int ablocks = (n + 15) / 16;     // 16 nodes per block (4 waves x 4)
  // layer 1
  k_gemm<true, 256><<<gblocks, 256, 0, stream>>>(x, W1T, dinv, scaled, n);
  k_aggregate<<<ablocks, 256, 0, stream>>>(scaled, dinv, b1, row_start, csr_src, hbuf, n, 0);
  k_aggregate<<<ablocks, 256, 0, stream>>>(scaled, dinv, b1, row_start, csr_src, hbuf, n, 1);
  // layer 2
  k_gemm<false, 128><<<gblocks, 256, 0, stream>>>(hbuf, W2T, dinv, scaled, n);
  k_aggregate<<<ablocks, 256, 0, stream>>>(scaled, dinv, b2, row_start, csr_src, hbuf, n, 0);
  k_aggregate<<<ablocks, 256, 0, stream>>>(scaled, dinv, b2, row_start, csr_src, hbuf, n, 1);
  // fused skip + final
  k_gemm_dual<256, 128><<<gblocks, 256, 0, stream>>>(x, WsT, hbuf, WfT, bsk, bf_, (float*)d_out, n);
}

// Round 13
// 166.526 us; speedup vs baseline: 1.2118x; 1.2118x over previous
//
#include <hip/hip_runtime.h>
#include <hip/hip_bf16.h>
#include <stdint.h>

// ---------------------------------------------------------------------------
// TrafficGNN: 2-layer GCN + skip, N=50000, E=1.6M, dims 256->128->128.
// R13 = R11 (best, 171.5us) + cleanups:
//  - R12's half-row passes REVERTED (3rd refutation of pass-splitting: loop
//    iterations double, costs ~30us > ~8us capacity-miss savings). Aggregate
//    = R11: full 128B fp8 row, 2 nodes/wave, 32 lanes x 4B, 8-deep prefetch.
//  - k_wtall stays fused into k_wtcount (R12, harmless).
//  - k_btot_scan ELIMINATED: k_scatter scans btot in LDS per block;
//    k_bucket2csr reduces btot[0..b) for its own bs/be; row_start[n]=E
//    written by last bucket block. 10 -> 9 launches.
// ---------------------------------------------------------------------------

typedef __attribute__((ext_vector_type(8))) short bf16x8;
typedef __attribute__((ext_vector_type(4))) float f32x4;
typedef __attribute__((ext_vector_type(2))) float f32x2;

#define NB 392        // dst buckets (392*128 = 50176 >= 50000)
#define NPB 128       // nodes per bucket (pow2: bucket = dst>>7)
#define CHUNK 2048    // edges per k_count/k_scatter block

__device__ __forceinline__ short f2bf(float f) {
  uint32_t u = __float_as_uint(f);
  u += 0x7fffu + ((u >> 16) & 1u);   // round-to-nearest-even
  return (short)(u >> 16);
}

// --- fp8 e4m3fn encode/decode (HW cvt preferred, software fallback) ---------
#if __has_builtin(__builtin_amdgcn_cvt_pk_fp8_f32)
__device__ __forceinline__ uint32_t f32_to_fp8(float x) {
  return (uint32_t)__builtin_amdgcn_cvt_pk_fp8_f32(x, x, 0, false) & 0xffu;
}
#else
__device__ __forceinline__ uint32_t f32_to_fp8(float x) {
  uint32_t u = __float_as_uint(x);
  uint32_t s = (u >> 24) & 0x80u;
  float ax = fabsf(x);
  if (ax > 448.f) ax = 448.f;
  uint32_t b;
  if (ax < 0.015625f) {
    b = (uint32_t)(ax * 512.f + 0.5f);
    if (b > 8) b = 8;
  } else {
    uint32_t au = __float_as_uint(ax);
    uint32_t exp = au >> 23;
    uint32_t man = au & 0x7fffffu;
    uint32_t keep = man >> 20;
    uint32_t rem = man & 0xFFFFFu;
    uint32_t rnd = (rem > 0x80000u) || (rem == 0x80000u && (keep & 1u));
    uint32_t code = ((exp - 120u) << 3) | keep;
    code += rnd;
    if (code > 0x7Eu) code = 0x7Eu;
    b = code;
  }
  return b | s;
}
#endif

#if __has_builtin(__builtin_amdgcn_cvt_pk_f32_fp8)
template <bool HI>
__device__ __forceinline__ f32x2 fp8x2_to_f32(uint32_t u) {
  return __builtin_amdgcn_cvt_pk_f32_fp8((int)u, HI);   // HI is a literal
}
#else
__device__ __forceinline__ float fp8_to_f32_1(uint32_t b) {
  uint32_t s = (b & 0x80u) << 24;
  uint32_t e = (b >> 3) & 0xFu;
  uint32_t m = b & 7u;
  float v = e ? __uint_as_float(((e + 120u) << 23) | (m << 20))
              : (float)m * 0.001953125f;
  return __uint_as_float(__float_as_uint(v) | s);
}
template <bool HI>
__device__ __forceinline__ f32x2 fp8x2_to_f32(uint32_t u) {
  uint32_t h = HI ? (u >> 16) : u;
  f32x2 r;
  r[0] = fp8_to_f32_1(h & 0xffu);
  r[1] = fp8_to_f32_1((h >> 8) & 0xffu);
  return r;
}
#endif

// --- fused: per-chunk bucket histogram (blocks [0,nblk)) + weight transpose
//     (blocks [nblk, nblk+384)) ---------------------------------------------
__global__ __launch_bounds__(256) void k_wtcount(const int* __restrict__ dst,
                                                 int* __restrict__ count, int E, int nblk,
                                                 const float* __restrict__ W1,
                                                 const float* __restrict__ W2,
                                                 const float* __restrict__ Ws,
                                                 const float* __restrict__ Wf,
                                                 short* __restrict__ W1T,
                                                 short* __restrict__ W2T,
                                                 short* __restrict__ WsT,
                                                 short* __restrict__ WfT) {
  int t = threadIdx.x;
  if ((int)blockIdx.x >= nblk) {
    int i = ((int)blockIdx.x - nblk) * 256 + t;
    const float* W; short* WT; int K, off;
    if (i < 32768)      { W = W1; WT = W1T; K = 256; off = 0; }
    else if (i < 49152) { W = W2; WT = W2T; K = 128; off = 32768; }
    else if (i < 81920) { W = Ws; WT = WsT; K = 256; off = 49152; }
    else if (i < 98304) { W = Wf; WT = WfT; K = 128; off = 81920; }
    else return;
    int j = i - off;
    int k = j >> 7, nn = j & 127;           // N = 128 always
    WT[nn * K + k] = f2bf(W[j]);
    return;
  }
  __shared__ int h[512];
  h[t] = 0; h[t + 256] = 0;
  __syncthreads();
  int base = blockIdx.x * CHUNK;
#pragma unroll
  for (int i = 0; i < CHUNK / 256; ++i) {
    int idx = base + i * 256 + t;
    if (idx < E) atomicAdd(&h[dst[idx] >> 7], 1);
  }
  __syncthreads();
  if (t < NB) count[blockIdx.x * NB + t] = h[t];
  if (t + 256 < NB) count[blockIdx.x * NB + t + 256] = h[t + 256];
}

// --- stage 2: per-bucket exclusive scan over chunks (nblk <= 1024) ----------
__global__ __launch_bounds__(1024) void k_colscan(int* __restrict__ count,
                                                  int* __restrict__ btot, int nblk) {
  __shared__ int s[1024];
  int t = threadIdx.x, b = blockIdx.x;
  int v = (t < nblk) ? count[t * NB + b] : 0;
  s[t] = v;
  __syncthreads();
  for (int off = 1; off < 1024; off <<= 1) {
    int u = (t >= off) ? s[t - off] : 0;
    __syncthreads();
    s[t] += u;
    __syncthreads();
  }
  if (t < nblk) count[t * NB + b] = s[t] - v;   // exclusive within column
  if (t == 1023) btot[b] = s[1023];
}

// --- stage 3: LDS multisplit + coalesced copy-out; bucket_start from btot ---
__global__ __launch_bounds__(256) void k_scatter(const int* __restrict__ src,
                                                 const int* __restrict__ dst,
                                                 const int* __restrict__ colscan,
                                                 const int* __restrict__ btot,
                                                 int* __restrict__ pairs, int E) {
  __shared__ int gcur[NB];
  __shared__ int abt[512];
  __shared__ int bst[512];
  __shared__ int hist[512];
  __shared__ int sstart[512];
  __shared__ int cur[512];
  __shared__ int p[256];
  __shared__ int2 stage[CHUNK];
  __shared__ int tot;
  int t = threadIdx.x;
  // exclusive scan of btot (NB entries, zero-padded to 512) -> bst
  abt[t] = (t < NB) ? btot[t] : 0;
  abt[t + 256] = (t + 256 < NB) ? btot[t + 256] : 0;
  __syncthreads();
  {
    int pv = abt[2 * t] + abt[2 * t + 1];
    p[t] = pv;
    __syncthreads();
    for (int off = 1; off < 256; off <<= 1) {
      int u = (t >= off) ? p[t - off] : 0;
      __syncthreads();
      p[t] += u;
      __syncthreads();
    }
    int pex = p[t] - pv;
    bst[2 * t] = pex;
    bst[2 * t + 1] = pex + abt[2 * t];
  }
  __syncthreads();
  if (t < NB) gcur[t] = bst[t] + colscan[blockIdx.x * NB + t];
  if (t + 256 < NB) gcur[t + 256] = bst[t + 256] + colscan[blockIdx.x * NB + t + 256];
  hist[t] = 0; hist[t + 256] = 0;
  __syncthreads();
  int base = blockIdx.x * CHUNK;
  int mys[CHUNK / 256], myd[CHUNK / 256];
#pragma unroll
  for (int i = 0; i < CHUNK / 256; ++i) {
    int idx = base + i * 256 + t;
    if (idx < E) {
      mys[i] = src[idx]; myd[i] = dst[idx];
      atomicAdd(&hist[myd[i] >> 7], 1);
    } else myd[i] = -1;
  }
  __syncthreads();
  // exclusive scan of hist[512] with 256 threads (pair trick)
  int pv = hist[2 * t] + hist[2 * t + 1];
  p[t] = pv;
  __syncthreads();
  for (int off = 1; off < 256; off <<= 1) {
    int u = (t >= off) ? p[t - off] : 0;
    __syncthreads();
    p[t] += u;
    __syncthreads();
  }
  int pex = p[t] - pv;
  sstart[2 * t] = pex;                   cur[2 * t] = pex;
  sstart[2 * t + 1] = pex + hist[2 * t]; cur[2 * t + 1] = pex + hist[2 * t];
  if (t == 255) tot = p[255];
  __syncthreads();
#pragma unroll
  for (int i = 0; i < CHUNK / 256; ++i) {
    if (myd[i] >= 0) {
      int slot = atomicAdd(&cur[myd[i] >> 7], 1);
      stage[slot] = int2{mys[i], myd[i]};
    }
  }
  __syncthreads();
  // coalesced copy-out: consecutive slots of a segment -> consecutive global
  int total = tot;
  for (int i = t; i < total; i += 256) {
    int2 pr = stage[i];
    int b = pr.y >> 7;
    pairs[gcur[b] + (i - sstart[b])] = (pr.x << 7) | (pr.y & 127);
  }
}

// --- stage 4: bucket -> CSR (+ row_start, dinv); bs/be reduced from btot ----
__global__ __launch_bounds__(256) void k_bucket2csr(const int* __restrict__ pairs,
                                                    const int* __restrict__ btot,
                                                    int* __restrict__ row_start,
                                                    float* __restrict__ dinv,
                                                    int* __restrict__ csr_src,
                                                    int n, int E) {
  __shared__ int red[256];
  __shared__ int cnt[NPB];
  __shared__ int scn[NPB];
  __shared__ int cur[NPB];
  int b = blockIdx.x, t = threadIdx.x;
  // bs = sum(btot[0..b))
  int a0 = (t < b) ? btot[t] : 0;
  int a1 = (t + 256 < b) ? btot[t + 256] : 0;
  red[t] = a0 + a1;
  __syncthreads();
  for (int off = 128; off; off >>= 1) {
    if (t < off) red[t] += red[t + off];
    __syncthreads();
  }
  int bs = red[0];
  int be = bs + btot[b];
  int nodeBase = b << 7;
  if (b == NB - 1 && t == 0) row_start[n] = E;
  if (t < NPB) cnt[t] = 0;
  __syncthreads();
  for (int i = bs + t; i < be; i += 256)
    atomicAdd(&cnt[pairs[i] & 127], 1);
  __syncthreads();
  int v = (t < NPB) ? cnt[t] : 0;
  if (t < NPB) scn[t] = v;
  __syncthreads();
  for (int off = 1; off < NPB; off <<= 1) {
    int u = (t >= off && t < NPB) ? scn[t - off] : 0;
    __syncthreads();
    if (t < NPB) scn[t] += u;
    __syncthreads();
  }
  if (t < NPB) {
    int ex = scn[t] - v;
    cur[t] = ex;
    int node = nodeBase + t;
    if (node < n) {
      row_start[node] = bs + ex;
      dinv[node] = rsqrtf((float)(v + 1));   // +1 self-loop
    }
  }
  __syncthreads();
  for (int i = bs + t; i < be; i += 256) {
    int packed = pairs[i];
    int pos = bs + atomicAdd(&cur[packed & 127], 1);
    csr_src[pos] = packed >> 7;
  }
}

// === LDS-staged panel GEMM ==================================================
__device__ __forceinline__ void stage_panel(short* lB, const short* __restrict__ BT,
                                            int K, int p, int t) {
#pragma unroll
  for (int i = 0; i < 8; ++i) {
    int ch = t + i * 256;            // 2048 chunks of 8 shorts
    int nrow = ch >> 4;
    int kl = (ch & 15) << 3;         // local k (shorts)
    bf16x8 v = *(const bf16x8*)(BT + (size_t)nrow * K + p * 128 + kl);
    int byte = nrow * 256 + ((kl << 1) ^ ((nrow & 7) << 4));
    *(bf16x8*)((char*)lB + byte) = v;
  }
}

__device__ __forceinline__ bf16x8 lds_bfrag(const short* lB, int c, int r, int g, int k0) {
  int nrow = c * 16 + r;
  int byte = nrow * 256 + (((k0 + g * 8) << 1) ^ ((nrow & 7) << 4));
  return *(const bf16x8*)((const char*)lB + byte);
}

__device__ __forceinline__ bf16x8 load_a_f32(const float* A, int row, int K, int kidx) {
  const f32x4* p = (const f32x4*)(A + (size_t)row * K + kidx);
  f32x4 v0 = p[0], v1 = p[1];
  bf16x8 a;
  a[0] = f2bf(v0[0]); a[1] = f2bf(v0[1]); a[2] = f2bf(v0[2]); a[3] = f2bf(v0[3]);
  a[4] = f2bf(v1[0]); a[5] = f2bf(v1[1]); a[6] = f2bf(v1[2]); a[7] = f2bf(v1[3]);
  return a;
}

// k_gemm: [M,K] @ WT[128,K] -> scaled (fp8 bytes), epilogue *dinv[row]
template <bool A_F32, int K>
__global__ __launch_bounds__(256, 4) void k_gemm(const void* __restrict__ Av,
                                                 const short* __restrict__ BT,
                                                 const float* __restrict__ dinv,
                                                 uint8_t* __restrict__ outv, int M) {
  __shared__ short lB[128 * 128];   // 32KB
  int t = threadIdx.x;
  int wave = t >> 6, lane = t & 63;
  int r = lane & 15, g = lane >> 4;
  int rowBase = blockIdx.x * 128 + wave * 32;

  f32x4 acc[2][8];
#pragma unroll
  for (int m = 0; m < 2; ++m)
#pragma unroll
    for (int c = 0; c < 8; ++c) acc[m][c] = f32x4{0.f, 0.f, 0.f, 0.f};

  int arow[2];
#pragma unroll
  for (int m = 0; m < 2; ++m) {
    int row = rowBase + m * 16 + r;
    arow[m] = (row < M) ? row : (M - 1);   // clamp: no early return (barriers)
  }

  for (int p = 0; p < K / 128; ++p) {
    stage_panel(lB, BT, K, p, t);
    __syncthreads();
#pragma unroll
    for (int k0 = 0; k0 < 128; k0 += 32) {
      int kidx = p * 128 + k0 + g * 8;
      bf16x8 af[2];
#pragma unroll
      for (int m = 0; m < 2; ++m) {
        if constexpr (A_F32) af[m] = load_a_f32((const float*)Av, arow[m], K, kidx);
        else af[m] = *(const bf16x8*)((const short*)Av + (size_t)arow[m] * K + kidx);
      }
#pragma unroll
      for (int c = 0; c < 8; ++c) {
        bf16x8 bfrag = lds_bfrag(lB, c, r, g, k0);
#pragma unroll
        for (int m = 0; m < 2; ++m)
          acc[m][c] = __builtin_amdgcn_mfma_f32_16x16x32_bf16(af[m], bfrag, acc[m][c], 0, 0, 0);
      }
    }
    __syncthreads();
  }

#pragma unroll
  for (int m = 0; m < 2; ++m)
#pragma unroll
    for (int j = 0; j < 4; ++j) {
      int rr = rowBase + m * 16 + g * 4 + j;
      if (rr < M) {
        float dv = dinv[rr];
#pragma unroll
        for (int c = 0; c < 8; ++c)
          outv[(size_t)rr * 128 + c * 16 + r] = (uint8_t)f32_to_fp8(acc[m][c][j] * dv);
      }
    }
}

// --- fused final: out = x@WsT + h2@WfT + (bs+bf), 3 panels through 32KB -----
template <int K1, int K2>
__global__ __launch_bounds__(256, 4) void k_gemm_dual(const float* __restrict__ A1,
                                                      const short* __restrict__ B1T,
                                                      const short* __restrict__ A2,
                                                      const short* __restrict__ B2T,
                                                      const float* __restrict__ bias1,
                                                      const float* __restrict__ bias2,
                                                      float* __restrict__ out, int M) {
  __shared__ short lB[128 * 128];   // 32KB
  int t = threadIdx.x;
  int wave = t >> 6, lane = t & 63;
  int r = lane & 15, g = lane >> 4;
  int rowBase = blockIdx.x * 128 + wave * 32;

  f32x4 acc[2][8];
#pragma unroll
  for (int m = 0; m < 2; ++m)
#pragma unroll
    for (int c = 0; c < 8; ++c) acc[m][c] = f32x4{0.f, 0.f, 0.f, 0.f};

  int arow[2];
#pragma unroll
  for (int m = 0; m < 2; ++m) {
    int row = rowBase + m * 16 + r;
    arow[m] = (row < M) ? row : (M - 1);
  }

  for (int p = 0; p < K1 / 128; ++p) {
    stage_panel(lB, B1T, K1, p, t);
    __syncthreads();
#pragma unroll
    for (int k0 = 0; k0 < 128; k0 += 32) {
      int kidx = p * 128 + k0 + g * 8;
      bf16x8 af[2];
#pragma unroll
      for (int m = 0; m < 2; ++m) af[m] = load_a_f32(A1, arow[m], K1, kidx);
#pragma unroll
      for (int c = 0; c < 8; ++c) {
        bf16x8 bfrag = lds_bfrag(lB, c, r, g, k0);
#pragma unroll
        for (int m = 0; m < 2; ++m)
          acc[m][c] = __builtin_amdgcn_mfma_f32_16x16x32_bf16(af[m], bfrag, acc[m][c], 0, 0, 0);
      }
    }
    __syncthreads();
  }
  for (int p = 0; p < K2 / 128; ++p) {
    stage_panel(lB, B2T, K2, p, t);
    __syncthreads();
#pragma unroll
    for (int k0 = 0; k0 < 128; k0 += 32) {
      int kidx = p * 128 + k0 + g * 8;
      bf16x8 af[2];
#pragma unroll
      for (int m = 0; m < 2; ++m)
        af[m] = *(const bf16x8*)(A2 + (size_t)arow[m] * K2 + kidx);
#pragma unroll
      for (int c = 0; c < 8; ++c) {
        bf16x8 bfrag = lds_bfrag(lB, c, r, g, k0);
#pragma unroll
        for (int m = 0; m < 2; ++m)
          acc[m][c] = __builtin_amdgcn_mfma_f32_16x16x32_bf16(af[m], bfrag, acc[m][c], 0, 0, 0);
      }
    }
    __syncthreads();
  }

#pragma unroll
  for (int m = 0; m < 2; ++m)
#pragma unroll
    for (int j = 0; j < 4; ++j) {
      int rr = rowBase + m * 16 + g * 4 + j;
      if (rr < M) {
#pragma unroll
        for (int c = 0; c < 8; ++c) {
          int cc = c * 16 + r;
          out[(size_t)rr * 128 + cc] = acc[m][c][j] + bias1[cc] + bias2[cc];
        }
      }
    }
}

// --- per-node CSR gather (fp8 rows): 2 nodes/wave, 32 lanes x 4B = 128B/row -
// Lane l covers feats [4l, 4l+4) decoded from one uint (4 fp8 bytes).
__global__ __launch_bounds__(256, 8) void k_aggregate(const uint8_t* __restrict__ scaled,
                                                      const float* __restrict__ dinv,
                                                      const float* __restrict__ bias,
                                                      const int* __restrict__ row_start,
                                                      const int* __restrict__ csr_src,
                                                      short* __restrict__ hout, int n) {
  int lane = threadIdx.x & 63;
  int l = lane & 31;                       // lane within half-wave
  int node = (blockIdx.x * 4 + (threadIdx.x >> 6)) * 2 + (lane >> 5);
  if (node >= n) return;
  const uint32_t* __restrict__ su = (const uint32_t*)scaled;  // row = 32 uints

  uint32_t u = su[(uint32_t)node * 32u + l];   // self loop
  f32x2 a0 = fp8x2_to_f32<false>(u), a1 = fp8x2_to_f32<true>(u);
  float s0 = a0[0], s1 = a0[1], s2 = a1[0], s3 = a1[1];

  int beg = row_start[node], end = row_start[node + 1];
  int deg = end - beg;
  int nfull = deg & ~7;
  int j = beg;
  if (nfull) {
    uint32_t offv[8];
#pragma unroll
    for (int q = 0; q < 8; ++q) offv[q] = (uint32_t)csr_src[beg + q] * 32u + l;
    for (int base = 8;; base += 8) {
      uint32_t v[8];
#pragma unroll
      for (int q = 0; q < 8; ++q) v[q] = su[offv[q]];
      bool more = (base < nfull);
      if (more) {
#pragma unroll
        for (int q = 0; q < 8; ++q) offv[q] = (uint32_t)csr_src[beg + base + q] * 32u + l;
      }
#pragma unroll
      for (int q = 0; q < 8; ++q) {
        f32x2 lo = fp8x2_to_f32<false>(v[q]), hi = fp8x2_to_f32<true>(v[q]);
        s0 += lo[0]; s1 += lo[1]; s2 += hi[0]; s3 += hi[1];
      }
      if (!more) break;
    }
    j = beg + nfull;
  }
  for (; j < end; ++j) {
    uint32_t v = su[(uint32_t)csr_src[j] * 32u + l];
    f32x2 lo = fp8x2_to_f32<false>(v), hi = fp8x2_to_f32<true>(v);
    s0 += lo[0]; s1 += lo[1]; s2 += hi[0]; s3 += hi[1];
  }

  float di = dinv[node];
  int col = l * 4;
  float h0 = fmaxf(fmaf(s0, di, bias[col]), 0.f);
  float h1 = fmaxf(fmaf(s1, di, bias[col + 1]), 0.f);
  float h2 = fmaxf(fmaf(s2, di, bias[col + 2]), 0.f);
  float h3 = fmaxf(fmaf(s3, di, bias[col + 3]), 0.f);
  uint2 o;
  o.x = (uint32_t)(uint16_t)f2bf(h0) | ((uint32_t)(uint16_t)f2bf(h1) << 16);
  o.y = (uint32_t)(uint16_t)f2bf(h2) | ((uint32_t)(uint16_t)f2bf(h3) << 16);
  ((uint2*)hout)[(uint32_t)node * 32u + l] = o;
}

extern "C" void kernel_launch(void* const* d_in, const int* in_sizes, int n_in,
                              void* d_out, int out_size, void* d_ws, size_t ws_size,
                              hipStream_t stream) {
  const float* x  = (const float*)d_in[0];
  const int* ei   = (const int*)d_in[1];
  const float* W1 = (const float*)d_in[2];
  const float* b1 = (const float*)d_in[3];
  const float* W2 = (const float*)d_in[4];
  const float* b2 = (const float*)d_in[5];
  const float* Wsk = (const float*)d_in[6];
  const float* bsk = (const float*)d_in[7];
  const float* Wf = (const float*)d_in[8];
  const float* bf_ = (const float*)d_in[9];

  const int n = in_sizes[0] / 256;
  const int E = in_sizes[1] / 2;
  const int* src = ei;
  const int* dst = ei + E;

  char* p = (char*)d_ws;
  auto alloc = [&](size_t bytes) -> char* {
    char* r = p;
    p += (bytes + 255) & ~(size_t)255;
    return r;
  };
  // pairs (6.4MB packed, dead after k_bucket2csr) aliases scaled (6.4MB fp8)
  char* buf0       = alloc((size_t)E * 4);                // 6.4 MB
  int* pairs       = (int*)buf0;
  uint8_t* scaled  = (uint8_t*)buf0;
  short* hbuf      = (short*)alloc((size_t)n * 128 * 2);  // 12.8 MB
  int* csr_src     = (int*)alloc((size_t)E * 4);          // 6.4 MB
  int* count       = (int*)alloc((size_t)1024 * NB * 4);  // 1.6 MB max
  int* btot        = (int*)alloc(NB * 4);
  int* row_start   = (int*)alloc((size_t)(n + 1) * 4);
  float* dinv      = (float*)alloc((size_t)n * 4);
  short* W1T       = (short*)alloc(256 * 128 * 2);
  short* W2T       = (short*)alloc(128 * 128 * 2);
  short* WsT       = (short*)alloc(256 * 128 * 2);
  short* WfT       = (short*)alloc(128 * 128 * 2);

  const int nblk = (E + CHUNK - 1) / CHUNK;   // 782 for E=1.6M (<= 1024)
  const int wtblk = (98304 + 255) / 256;      // 384
  k_wtcount<<<nblk + wtblk, 256, 0, stream>>>(dst, count, E, nblk,
                                              W1, W2, Wsk, Wf, W1T, W2T, WsT, WfT);
  k_colscan<<<NB, 1024, 0, stream>>>(count, btot, nblk);
  k_scatter<<<nblk, 256, 0, stream>>>(src, dst, count, btot, pairs, E);
  k_bucket2csr<<<NB, 256, 0, stream>>>(pairs, btot, row_start, dinv, csr_src, n, E);

  const int gblocks = (n + 127) / 128;   // 391
  const int ablocks = (n + 7) / 8;       // 8 nodes per block (4 waves x 2)
  // layer 1
  k_gemm<true, 256><<<gblocks, 256, 0, stream>>>(x, W1T, dinv, scaled, n);
  k_aggregate<<<ablocks, 256, 0, stream>>>(scaled, dinv, b1, row_start, csr_src, hbuf, n);
  // layer 2
  k_gemm<false, 128><<<gblocks, 256, 0, stream>>>(hbuf, W2T, dinv, scaled, n);
  k_aggregate<<<ablocks, 256, 0, stream>>>(scaled, dinv, b2, row_start, csr_src, hbuf, n);
  // fused skip + final
  k_gemm_dual<256, 128><<<gblocks, 256, 0, stream>>>(x, WsT, hbuf, WfT, bsk, bf_, (float*)d_out, n);
}

// Round 14
// 154.801 us; speedup vs baseline: 1.3035x; 1.0757x over previous
//
#include <hip/hip_runtime.h>
#include <hip/hip_bf16.h>
#include <stdint.h>

// ---------------------------------------------------------------------------
// TrafficGNN: 2-layer GCN + skip, N=50000, E=1.6M, dims 256->128->128.
// R14 changes vs R13 (166.5us):
//  - x (51.2MB f32) was read TWICE (gemm L1 + gemm_dual K1 = ~102MB of ~250MB
//    total traffic). k_gemm_l1s fuses both x-consumers: A-tile loaded ONCE
//    into registers (afs[4][2], static idx), both B panels (W1T->scaled fp8,
//    WsT->d_out f32+bias) run through the same 32KB LDS sequentially.
//  - final GEMM -> k_gemm_add (h2@Wf += into d_out): +25.6MB RMW read,
//    -51.2MB x read. Net -25.6MB.
//  - sort + aggregate = R13 exactly.
// ---------------------------------------------------------------------------

typedef __attribute__((ext_vector_type(8))) short bf16x8;
typedef __attribute__((ext_vector_type(4))) float f32x4;
typedef __attribute__((ext_vector_type(2))) float f32x2;

#define NB 392        // dst buckets (392*128 = 50176 >= 50000)
#define NPB 128       // nodes per bucket (pow2: bucket = dst>>7)
#define CHUNK 2048    // edges per k_count/k_scatter block

__device__ __forceinline__ short f2bf(float f) {
  uint32_t u = __float_as_uint(f);
  u += 0x7fffu + ((u >> 16) & 1u);   // round-to-nearest-even
  return (short)(u >> 16);
}

// --- fp8 e4m3fn encode/decode (HW cvt preferred, software fallback) ---------
#if __has_builtin(__builtin_amdgcn_cvt_pk_fp8_f32)
__device__ __forceinline__ uint32_t f32_to_fp8(float x) {
  return (uint32_t)__builtin_amdgcn_cvt_pk_fp8_f32(x, x, 0, false) & 0xffu;
}
#else
__device__ __forceinline__ uint32_t f32_to_fp8(float x) {
  uint32_t u = __float_as_uint(x);
  uint32_t s = (u >> 24) & 0x80u;
  float ax = fabsf(x);
  if (ax > 448.f) ax = 448.f;
  uint32_t b;
  if (ax < 0.015625f) {
    b = (uint32_t)(ax * 512.f + 0.5f);
    if (b > 8) b = 8;
  } else {
    uint32_t au = __float_as_uint(ax);
    uint32_t exp = au >> 23;
    uint32_t man = au & 0x7fffffu;
    uint32_t keep = man >> 20;
    uint32_t rem = man & 0xFFFFFu;
    uint32_t rnd = (rem > 0x80000u) || (rem == 0x80000u && (keep & 1u));
    uint32_t code = ((exp - 120u) << 3) | keep;
    code += rnd;
    if (code > 0x7Eu) code = 0x7Eu;
    b = code;
  }
  return b | s;
}
#endif

#if __has_builtin(__builtin_amdgcn_cvt_pk_f32_fp8)
template <bool HI>
__device__ __forceinline__ f32x2 fp8x2_to_f32(uint32_t u) {
  return __builtin_amdgcn_cvt_pk_f32_fp8((int)u, HI);   // HI is a literal
}
#else
__device__ __forceinline__ float fp8_to_f32_1(uint32_t b) {
  uint32_t s = (b & 0x80u) << 24;
  uint32_t e = (b >> 3) & 0xFu;
  uint32_t m = b & 7u;
  float v = e ? __uint_as_float(((e + 120u) << 23) | (m << 20))
              : (float)m * 0.001953125f;
  return __uint_as_float(__float_as_uint(v) | s);
}
template <bool HI>
__device__ __forceinline__ f32x2 fp8x2_to_f32(uint32_t u) {
  uint32_t h = HI ? (u >> 16) : u;
  f32x2 r;
  r[0] = fp8_to_f32_1(h & 0xffu);
  r[1] = fp8_to_f32_1((h >> 8) & 0xffu);
  return r;
}
#endif

// --- fused: per-chunk bucket histogram (blocks [0,nblk)) + weight transpose
//     (blocks [nblk, nblk+384)) ---------------------------------------------
__global__ __launch_bounds__(256) void k_wtcount(const int* __restrict__ dst,
                                                 int* __restrict__ count, int E, int nblk,
                                                 const float* __restrict__ W1,
                                                 const float* __restrict__ W2,
                                                 const float* __restrict__ Ws,
                                                 const float* __restrict__ Wf,
                                                 short* __restrict__ W1T,
                                                 short* __restrict__ W2T,
                                                 short* __restrict__ WsT,
                                                 short* __restrict__ WfT) {
  int t = threadIdx.x;
  if ((int)blockIdx.x >= nblk) {
    int i = ((int)blockIdx.x - nblk) * 256 + t;
    const float* W; short* WT; int K, off;
    if (i < 32768)      { W = W1; WT = W1T; K = 256; off = 0; }
    else if (i < 49152) { W = W2; WT = W2T; K = 128; off = 32768; }
    else if (i < 81920) { W = Ws; WT = WsT; K = 256; off = 49152; }
    else if (i < 98304) { W = Wf; WT = WfT; K = 128; off = 81920; }
    else return;
    int j = i - off;
    int k = j >> 7, nn = j & 127;           // N = 128 always
    WT[nn * K + k] = f2bf(W[j]);
    return;
  }
  __shared__ int h[512];
  h[t] = 0; h[t + 256] = 0;
  __syncthreads();
  int base = blockIdx.x * CHUNK;
#pragma unroll
  for (int i = 0; i < CHUNK / 256; ++i) {
    int idx = base + i * 256 + t;
    if (idx < E) atomicAdd(&h[dst[idx] >> 7], 1);
  }
  __syncthreads();
  if (t < NB) count[blockIdx.x * NB + t] = h[t];
  if (t + 256 < NB) count[blockIdx.x * NB + t + 256] = h[t + 256];
}

// --- stage 2: per-bucket exclusive scan over chunks (nblk <= 1024) ----------
__global__ __launch_bounds__(1024) void k_colscan(int* __restrict__ count,
                                                  int* __restrict__ btot, int nblk) {
  __shared__ int s[1024];
  int t = threadIdx.x, b = blockIdx.x;
  int v = (t < nblk) ? count[t * NB + b] : 0;
  s[t] = v;
  __syncthreads();
  for (int off = 1; off < 1024; off <<= 1) {
    int u = (t >= off) ? s[t - off] : 0;
    __syncthreads();
    s[t] += u;
    __syncthreads();
  }
  if (t < nblk) count[t * NB + b] = s[t] - v;   // exclusive within column
  if (t == 1023) btot[b] = s[1023];
}

// --- stage 3: LDS multisplit + coalesced copy-out; bucket_start from btot ---
__global__ __launch_bounds__(256) void k_scatter(const int* __restrict__ src,
                                                 const int* __restrict__ dst,
                                                 const int* __restrict__ colscan,
                                                 const int* __restrict__ btot,
                                                 int* __restrict__ pairs, int E) {
  __shared__ int gcur[NB];
  __shared__ int abt[512];
  __shared__ int bst[512];
  __shared__ int hist[512];
  __shared__ int sstart[512];
  __shared__ int cur[512];
  __shared__ int p[256];
  __shared__ int2 stage[CHUNK];
  __shared__ int tot;
  int t = threadIdx.x;
  // exclusive scan of btot (NB entries, zero-padded to 512) -> bst
  abt[t] = (t < NB) ? btot[t] : 0;
  abt[t + 256] = (t + 256 < NB) ? btot[t + 256] : 0;
  __syncthreads();
  {
    int pv = abt[2 * t] + abt[2 * t + 1];
    p[t] = pv;
    __syncthreads();
    for (int off = 1; off < 256; off <<= 1) {
      int u = (t >= off) ? p[t - off] : 0;
      __syncthreads();
      p[t] += u;
      __syncthreads();
    }
    int pex = p[t] - pv;
    bst[2 * t] = pex;
    bst[2 * t + 1] = pex + abt[2 * t];
  }
  __syncthreads();
  if (t < NB) gcur[t] = bst[t] + colscan[blockIdx.x * NB + t];
  if (t + 256 < NB) gcur[t + 256] = bst[t + 256] + colscan[blockIdx.x * NB + t + 256];
  hist[t] = 0; hist[t + 256] = 0;
  __syncthreads();
  int base = blockIdx.x * CHUNK;
  int mys[CHUNK / 256], myd[CHUNK / 256];
#pragma unroll
  for (int i = 0; i < CHUNK / 256; ++i) {
    int idx = base + i * 256 + t;
    if (idx < E) {
      mys[i] = src[idx]; myd[i] = dst[idx];
      atomicAdd(&hist[myd[i] >> 7], 1);
    } else myd[i] = -1;
  }
  __syncthreads();
  // exclusive scan of hist[512] with 256 threads (pair trick)
  int pv = hist[2 * t] + hist[2 * t + 1];
  p[t] = pv;
  __syncthreads();
  for (int off = 1; off < 256; off <<= 1) {
    int u = (t >= off) ? p[t - off] : 0;
    __syncthreads();
    p[t] += u;
    __syncthreads();
  }
  int pex = p[t] - pv;
  sstart[2 * t] = pex;                   cur[2 * t] = pex;
  sstart[2 * t + 1] = pex + hist[2 * t]; cur[2 * t + 1] = pex + hist[2 * t];
  if (t == 255) tot = p[255];
  __syncthreads();
#pragma unroll
  for (int i = 0; i < CHUNK / 256; ++i) {
    if (myd[i] >= 0) {
      int slot = atomicAdd(&cur[myd[i] >> 7], 1);
      stage[slot] = int2{mys[i], myd[i]};
    }
  }
  __syncthreads();
  // coalesced copy-out: consecutive slots of a segment -> consecutive global
  int total = tot;
  for (int i = t; i < total; i += 256) {
    int2 pr = stage[i];
    int b = pr.y >> 7;
    pairs[gcur[b] + (i - sstart[b])] = (pr.x << 7) | (pr.y & 127);
  }
}

// --- stage 4: bucket -> CSR (+ row_start, dinv); bs/be reduced from btot ----
__global__ __launch_bounds__(256) void k_bucket2csr(const int* __restrict__ pairs,
                                                    const int* __restrict__ btot,
                                                    int* __restrict__ row_start,
                                                    float* __restrict__ dinv,
                                                    int* __restrict__ csr_src,
                                                    int n, int E) {
  __shared__ int red[256];
  __shared__ int cnt[NPB];
  __shared__ int scn[NPB];
  __shared__ int cur[NPB];
  int b = blockIdx.x, t = threadIdx.x;
  // bs = sum(btot[0..b))
  int a0 = (t < b) ? btot[t] : 0;
  int a1 = (t + 256 < b) ? btot[t + 256] : 0;
  red[t] = a0 + a1;
  __syncthreads();
  for (int off = 128; off; off >>= 1) {
    if (t < off) red[t] += red[t + off];
    __syncthreads();
  }
  int bs = red[0];
  int be = bs + btot[b];
  int nodeBase = b << 7;
  if (b == NB - 1 && t == 0) row_start[n] = E;
  if (t < NPB) cnt[t] = 0;
  __syncthreads();
  for (int i = bs + t; i < be; i += 256)
    atomicAdd(&cnt[pairs[i] & 127], 1);
  __syncthreads();
  int v = (t < NPB) ? cnt[t] : 0;
  if (t < NPB) scn[t] = v;
  __syncthreads();
  for (int off = 1; off < NPB; off <<= 1) {
    int u = (t >= off && t < NPB) ? scn[t - off] : 0;
    __syncthreads();
    if (t < NPB) scn[t] += u;
    __syncthreads();
  }
  if (t < NPB) {
    int ex = scn[t] - v;
    cur[t] = ex;
    int node = nodeBase + t;
    if (node < n) {
      row_start[node] = bs + ex;
      dinv[node] = rsqrtf((float)(v + 1));   // +1 self-loop
    }
  }
  __syncthreads();
  for (int i = bs + t; i < be; i += 256) {
    int packed = pairs[i];
    int pos = bs + atomicAdd(&cur[packed & 127], 1);
    csr_src[pos] = packed >> 7;
  }
}

// === LDS-staged panel GEMM ==================================================
__device__ __forceinline__ void stage_panel(short* lB, const short* __restrict__ BT,
                                            int K, int p, int t) {
#pragma unroll
  for (int i = 0; i < 8; ++i) {
    int ch = t + i * 256;            // 2048 chunks of 8 shorts
    int nrow = ch >> 4;
    int kl = (ch & 15) << 3;         // local k (shorts)
    bf16x8 v = *(const bf16x8*)(BT + (size_t)nrow * K + p * 128 + kl);
    int byte = nrow * 256 + ((kl << 1) ^ ((nrow & 7) << 4));
    *(bf16x8*)((char*)lB + byte) = v;
  }
}

__device__ __forceinline__ bf16x8 lds_bfrag(const short* lB, int c, int r, int g, int k0) {
  int nrow = c * 16 + r;
  int byte = nrow * 256 + (((k0 + g * 8) << 1) ^ ((nrow & 7) << 4));
  return *(const bf16x8*)((const char*)lB + byte);
}

__device__ __forceinline__ bf16x8 load_a_f32(const float* A, int row, int K, int kidx) {
  const f32x4* p = (const f32x4*)(A + (size_t)row * K + kidx);
  f32x4 v0 = p[0], v1 = p[1];
  bf16x8 a;
  a[0] = f2bf(v0[0]); a[1] = f2bf(v0[1]); a[2] = f2bf(v0[2]); a[3] = f2bf(v0[3]);
  a[4] = f2bf(v1[0]); a[5] = f2bf(v1[1]); a[6] = f2bf(v1[2]); a[7] = f2bf(v1[3]);
  return a;
}

// --- fused L1 + skip: x read ONCE. scaled=fp8((x@W1)*dinv); out=x@Ws+bias ---
__global__ __launch_bounds__(256, 2) void k_gemm_l1s(const float* __restrict__ x,
                                                     const short* __restrict__ B1T,
                                                     const short* __restrict__ B2T,
                                                     const float* __restrict__ dinv,
                                                     const float* __restrict__ bias1,
                                                     const float* __restrict__ bias2,
                                                     uint8_t* __restrict__ scaled,
                                                     float* __restrict__ out, int M) {
  __shared__ short lB[128 * 128];   // 32KB
  int t = threadIdx.x;
  int wave = t >> 6, lane = t & 63;
  int r = lane & 15, g = lane >> 4;
  int rowBase = blockIdx.x * 128 + wave * 32;

  f32x4 acc1[2][8], acc2[2][8];
#pragma unroll
  for (int m = 0; m < 2; ++m)
#pragma unroll
    for (int c = 0; c < 8; ++c) {
      acc1[m][c] = f32x4{0.f, 0.f, 0.f, 0.f};
      acc2[m][c] = f32x4{0.f, 0.f, 0.f, 0.f};
    }

  int arow[2];
#pragma unroll
  for (int m = 0; m < 2; ++m) {
    int row = rowBase + m * 16 + r;
    arow[m] = (row < M) ? row : (M - 1);   // clamp: no early return (barriers)
  }

  for (int p = 0; p < 2; ++p) {            // K=256: 2 panels of 128
    bf16x8 afs[4][2];                      // A-frags for this panel, loaded once
#pragma unroll
    for (int kk = 0; kk < 4; ++kk) {
      int kidx = p * 128 + kk * 32 + g * 8;
#pragma unroll
      for (int m = 0; m < 2; ++m) afs[kk][m] = load_a_f32(x, arow[m], 256, kidx);
    }
    stage_panel(lB, B1T, 256, p, t);
    __syncthreads();
#pragma unroll
    for (int kk = 0; kk < 4; ++kk)
#pragma unroll
      for (int c = 0; c < 8; ++c) {
        bf16x8 bfrag = lds_bfrag(lB, c, r, g, kk * 32);
#pragma unroll
        for (int m = 0; m < 2; ++m)
          acc1[m][c] = __builtin_amdgcn_mfma_f32_16x16x32_bf16(afs[kk][m], bfrag, acc1[m][c], 0, 0, 0);
      }
    __syncthreads();
    stage_panel(lB, B2T, 256, p, t);
    __syncthreads();
#pragma unroll
    for (int kk = 0; kk < 4; ++kk)
#pragma unroll
      for (int c = 0; c < 8; ++c) {
        bf16x8 bfrag = lds_bfrag(lB, c, r, g, kk * 32);
#pragma unroll
        for (int m = 0; m < 2; ++m)
          acc2[m][c] = __builtin_amdgcn_mfma_f32_16x16x32_bf16(afs[kk][m], bfrag, acc2[m][c], 0, 0, 0);
      }
    __syncthreads();
  }

#pragma unroll
  for (int m = 0; m < 2; ++m)
#pragma unroll
    for (int j = 0; j < 4; ++j) {
      int rr = rowBase + m * 16 + g * 4 + j;
      if (rr < M) {
        float dv = dinv[rr];
#pragma unroll
        for (int c = 0; c < 8; ++c) {
          int cc = c * 16 + r;
          scaled[(size_t)rr * 128 + cc] = (uint8_t)f32_to_fp8(acc1[m][c][j] * dv);
          out[(size_t)rr * 128 + cc] = acc2[m][c][j] + bias1[cc] + bias2[cc];
        }
      }
    }
}

// k_gemm: [M,K] @ WT[128,K] -> scaled (fp8 bytes), epilogue *dinv[row]
template <bool A_F32, int K>
__global__ __launch_bounds__(256, 4) void k_gemm(const void* __restrict__ Av,
                                                 const short* __restrict__ BT,
                                                 const float* __restrict__ dinv,
                                                 uint8_t* __restrict__ outv, int M) {
  __shared__ short lB[128 * 128];   // 32KB
  int t = threadIdx.x;
  int wave = t >> 6, lane = t & 63;
  int r = lane & 15, g = lane >> 4;
  int rowBase = blockIdx.x * 128 + wave * 32;

  f32x4 acc[2][8];
#pragma unroll
  for (int m = 0; m < 2; ++m)
#pragma unroll
    for (int c = 0; c < 8; ++c) acc[m][c] = f32x4{0.f, 0.f, 0.f, 0.f};

  int arow[2];
#pragma unroll
  for (int m = 0; m < 2; ++m) {
    int row = rowBase + m * 16 + r;
    arow[m] = (row < M) ? row : (M - 1);   // clamp: no early return (barriers)
  }

  for (int p = 0; p < K / 128; ++p) {
    stage_panel(lB, BT, K, p, t);
    __syncthreads();
#pragma unroll
    for (int k0 = 0; k0 < 128; k0 += 32) {
      int kidx = p * 128 + k0 + g * 8;
      bf16x8 af[2];
#pragma unroll
      for (int m = 0; m < 2; ++m) {
        if constexpr (A_F32) af[m] = load_a_f32((const float*)Av, arow[m], K, kidx);
        else af[m] = *(const bf16x8*)((const short*)Av + (size_t)arow[m] * K + kidx);
      }
#pragma unroll
      for (int c = 0; c < 8; ++c) {
        bf16x8 bfrag = lds_bfrag(lB, c, r, g, k0);
#pragma unroll
        for (int m = 0; m < 2; ++m)
          acc[m][c] = __builtin_amdgcn_mfma_f32_16x16x32_bf16(af[m], bfrag, acc[m][c], 0, 0, 0);
      }
    }
    __syncthreads();
  }

#pragma unroll
  for (int m = 0; m < 2; ++m)
#pragma unroll
    for (int j = 0; j < 4; ++j) {
      int rr = rowBase + m * 16 + g * 4 + j;
      if (rr < M) {
        float dv = dinv[rr];
#pragma unroll
        for (int c = 0; c < 8; ++c)
          outv[(size_t)rr * 128 + c * 16 + r] = (uint8_t)f32_to_fp8(acc[m][c][j] * dv);
      }
    }
}

// --- final: out += h2@WfT (RMW into d_out) ---------------------------------
__global__ __launch_bounds__(256, 4) void k_gemm_add(const short* __restrict__ A,
                                                     const short* __restrict__ BT,
                                                     float* __restrict__ out, int M) {
  __shared__ short lB[128 * 128];   // 32KB
  int t = threadIdx.x;
  int wave = t >> 6, lane = t & 63;
  int r = lane & 15, g = lane >> 4;
  int rowBase = blockIdx.x * 128 + wave * 32;

  f32x4 acc[2][8];
#pragma unroll
  for (int m = 0; m < 2; ++m)
#pragma unroll
    for (int c = 0; c < 8; ++c) acc[m][c] = f32x4{0.f, 0.f, 0.f, 0.f};

  int arow[2];
#pragma unroll
  for (int m = 0; m < 2; ++m) {
    int row = rowBase + m * 16 + r;
    arow[m] = (row < M) ? row : (M - 1);
  }

  stage_panel(lB, BT, 128, 0, t);
  __syncthreads();
#pragma unroll
  for (int k0 = 0; k0 < 128; k0 += 32) {
    int kidx = k0 + g * 8;
    bf16x8 af[2];
#pragma unroll
    for (int m = 0; m < 2; ++m)
      af[m] = *(const bf16x8*)(A + (size_t)arow[m] * 128 + kidx);
#pragma unroll
    for (int c = 0; c < 8; ++c) {
      bf16x8 bfrag = lds_bfrag(lB, c, r, g, k0);
#pragma unroll
      for (int m = 0; m < 2; ++m)
        acc[m][c] = __builtin_amdgcn_mfma_f32_16x16x32_bf16(af[m], bfrag, acc[m][c], 0, 0, 0);
    }
  }

#pragma unroll
  for (int m = 0; m < 2; ++m)
#pragma unroll
    for (int j = 0; j < 4; ++j) {
      int rr = rowBase + m * 16 + g * 4 + j;
      if (rr < M) {
#pragma unroll
        for (int c = 0; c < 8; ++c) {
          float* o = out + (size_t)rr * 128 + c * 16 + r;
          *o += acc[m][c][j];
        }
      }
    }
}

// --- per-node CSR gather (fp8 rows): 2 nodes/wave, 32 lanes x 4B = 128B/row -
__global__ __launch_bounds__(256, 8) void k_aggregate(const uint8_t* __restrict__ scaled,
                                                      const float* __restrict__ dinv,
                                                      const float* __restrict__ bias,
                                                      const int* __restrict__ row_start,
                                                      const int* __restrict__ csr_src,
                                                      short* __restrict__ hout, int n) {
  int lane = threadIdx.x & 63;
  int l = lane & 31;                       // lane within half-wave
  int node = (blockIdx.x * 4 + (threadIdx.x >> 6)) * 2 + (lane >> 5);
  if (node >= n) return;
  const uint32_t* __restrict__ su = (const uint32_t*)scaled;  // row = 32 uints

  uint32_t u = su[(uint32_t)node * 32u + l];   // self loop
  f32x2 a0 = fp8x2_to_f32<false>(u), a1 = fp8x2_to_f32<true>(u);
  float s0 = a0[0], s1 = a0[1], s2 = a1[0], s3 = a1[1];

  int beg = row_start[node], end = row_start[node + 1];
  int deg = end - beg;
  int nfull = deg & ~7;
  int j = beg;
  if (nfull) {
    uint32_t offv[8];
#pragma unroll
    for (int q = 0; q < 8; ++q) offv[q] = (uint32_t)csr_src[beg + q] * 32u + l;
    for (int base = 8;; base += 8) {
      uint32_t v[8];
#pragma unroll
      for (int q = 0; q < 8; ++q) v[q] = su[offv[q]];
      bool more = (base < nfull);
      if (more) {
#pragma unroll
        for (int q = 0; q < 8; ++q) offv[q] = (uint32_t)csr_src[beg + base + q] * 32u + l;
      }
#pragma unroll
      for (int q = 0; q < 8; ++q) {
        f32x2 lo = fp8x2_to_f32<false>(v[q]), hi = fp8x2_to_f32<true>(v[q]);
        s0 += lo[0]; s1 += lo[1]; s2 += hi[0]; s3 += hi[1];
      }
      if (!more) break;
    }
    j = beg + nfull;
  }
  for (; j < end; ++j) {
    uint32_t v = su[(uint32_t)csr_src[j] * 32u + l];
    f32x2 lo = fp8x2_to_f32<false>(v), hi = fp8x2_to_f32<true>(v);
    s0 += lo[0]; s1 += lo[1]; s2 += hi[0]; s3 += hi[1];
  }

  float di = dinv[node];
  int col = l * 4;
  float h0 = fmaxf(fmaf(s0, di, bias[col]), 0.f);
  float h1 = fmaxf(fmaf(s1, di, bias[col + 1]), 0.f);
  float h2 = fmaxf(fmaf(s2, di, bias[col + 2]), 0.f);
  float h3 = fmaxf(fmaf(s3, di, bias[col + 3]), 0.f);
  uint2 o;
  o.x = (uint32_t)(uint16_t)f2bf(h0) | ((uint32_t)(uint16_t)f2bf(h1) << 16);
  o.y = (uint32_t)(uint16_t)f2bf(h2) | ((uint32_t)(uint16_t)f2bf(h3) << 16);
  ((uint2*)hout)[(uint32_t)node * 32u + l] = o;
}

extern "C" void kernel_launch(void* const* d_in, const int* in_sizes, int n_in,
                              void* d_out, int out_size, void* d_ws, size_t ws_size,
                              hipStream_t stream) {
  const float* x  = (const float*)d_in[0];
  const int* ei   = (const int*)d_in[1];
  const float* W1 = (const float*)d_in[2];
  const float* b1 = (const float*)d_in[3];
  const float* W2 = (const float*)d_in[4];
  const float* b2 = (const float*)d_in[5];
  const float* Wsk = (const float*)d_in[6];
  const float* bsk = (const float*)d_in[7];
  const float* Wf = (const float*)d_in[8];
  const float* bf_ = (const float*)d_in[9];

  const int n = in_sizes[0] / 256;
  const int E = in_sizes[1] / 2;
  const int* src = ei;
  const int* dst = ei + E;

  char* p = (char*)d_ws;
  auto alloc = [&](size_t bytes) -> char* {
    char* r = p;
    p += (bytes + 255) & ~(size_t)255;
    return r;
  };
  // pairs (6.4MB packed, dead after k_bucket2csr) aliases scaled (6.4MB fp8)
  char* buf0       = alloc((size_t)E * 4);                // 6.4 MB
  int* pairs       = (int*)buf0;
  uint8_t* scaled  = (uint8_t*)buf0;
  short* hbuf      = (short*)alloc((size_t)n * 128 * 2);  // 12.8 MB
  int* csr_src     = (int*)alloc((size_t)E * 4);          // 6.4 MB
  int* count       = (int*)alloc((size_t)1024 * NB * 4);  // 1.6 MB max
  int* btot        = (int*)alloc(NB * 4);
  int* row_start   = (int*)alloc((size_t)(n + 1) * 4);
  float* dinv      = (float*)alloc((size_t)n * 4);
  short* W1T       = (short*)alloc(256 * 128 * 2);
  short* W2T       = (short*)alloc(128 * 128 * 2);
  short* WsT       = (short*)alloc(256 * 128 * 2);
  short* WfT       = (short*)alloc(128 * 128 * 2);

  const int nblk = (E + CHUNK - 1) / CHUNK;   // 782 for E=1.6M (<= 1024)
  const int wtblk = (98304 + 255) / 256;      // 384
  k_wtcount<<<nblk + wtblk, 256, 0, stream>>>(dst, count, E, nblk,
                                              W1, W2, Wsk, Wf, W1T, W2T, WsT, WfT);
  k_colscan<<<NB, 1024, 0, stream>>>(count, btot, nblk);
  k_scatter<<<nblk, 256, 0, stream>>>(src, dst, count, btot, pairs, E);
  k_bucket2csr<<<NB, 256, 0, stream>>>(pairs, btot, row_start, dinv, csr_src, n, E);

  const int gblocks = (n + 127) / 128;   // 391
  const int ablocks = (n + 7) / 8;       // 8 nodes per block (4 waves x 2)
  // fused layer-1 GEMM + skip GEMM (x read once)
  k_gemm_l1s<<<gblocks, 256, 0, stream>>>(x, W1T, WsT, dinv, bsk, bf_, scaled, (float*)d_out, n);
  k_aggregate<<<ablocks, 256, 0, stream>>>(scaled, dinv, b1, row_start, csr_src, hbuf, n);
  // layer 2
  k_gemm<false, 128><<<gblocks, 256, 0, stream>>>(hbuf, W2T, dinv, scaled, n);
  k_aggregate<<<ablocks, 256, 0, stream>>>(scaled, dinv, b2, row_start, csr_src, hbuf, n);
  // final: out += h2@Wf
  k_gemm_add<<<gblocks, 256, 0, stream>>>(hbuf, WfT, (float*)d_out, n);
}